// Round 12
// baseline (231.877 us; speedup 1.0000x reference)
//
#include <hip/hip_runtime.h>

#define TT 4096
#define CC 1024
#define DD 128

typedef __attribute__((ext_vector_type(8))) short s16x8;
typedef __attribute__((ext_vector_type(4))) short s16x4;
typedef __attribute__((ext_vector_type(8))) __bf16 bf16x8;
typedef __attribute__((ext_vector_type(4))) float f32x4;
typedef __attribute__((ext_vector_type(2))) float f32x2;

__device__ __forceinline__ short f2bf(float f) {
    union { float f; unsigned u; } v; v.f = f;
    unsigned r = v.u + 0x7fffu + ((v.u >> 16) & 1u);
    return (short)(r >> 16);
}

__device__ __forceinline__ unsigned cvt_pk(float lo, float hi) {
    unsigned r;
    asm("v_cvt_pk_bf16_f32 %0, %1, %2" : "=v"(r) : "v"(lo), "v"(hi));
    return r;
}

__device__ __forceinline__ f32x4 mfma16(s16x8 a, s16x8 b, f32x4 c) {
    return __builtin_amdgcn_mfma_f32_16x16x32_bf16(
        __builtin_bit_cast(bf16x8, a), __builtin_bit_cast(bf16x8, b), c, 0, 0, 0);
}

__device__ __forceinline__ void gload_lds16(const short* g, short* l) {
    __builtin_amdgcn_global_load_lds(
        (const __attribute__((address_space(1))) void*)g,
        (__attribute__((address_space(3))) void*)l, 16, 0, 0);
}

// ---------------- kernel 0: transpose weights -> wT bf16 [3][D][C] ---------------
// wq gets D^-0.5 * log2(e) folded in -> softmax runs in base-2 (exp2f = 1 inst).
__global__ void wt_kernel(const float* __restrict__ wq, const float* __restrict__ wk,
                          const float* __restrict__ wv, short* __restrict__ wT) {
    int idx = blockIdx.x * 256 + threadIdx.x;   // 3*128*1024 = 393216 threads
    int d = idx & 127;
    int c = (idx >> 7) & 1023;
    int wsel = idx >> 17;
    const float* w = (wsel == 0) ? wq : (wsel == 1) ? wk : wv;
    float v = w[(size_t)c * DD + d];
    if (wsel == 0) v *= 0.08838834764831845f * 1.4426950408889634f;
    wT[(size_t)wsel * DD * CC + (size_t)d * CC + c] = f2bf(v);
}

// ---------------- kernel 1: fused QKV projection GEMM (unchanged) ----------------
__global__ __launch_bounds__(512)
void qkv_kernel(const float* __restrict__ x, const short* __restrict__ wT,
                short* __restrict__ qo, short* __restrict__ ko, short* __restrict__ vTo) {
    __shared__ short lw[2][384 * 64];   // 2 x 48KB
    const int mt = blockIdx.x;
    const int tid = threadIdx.x, lane = tid & 63, wid = tid >> 6;
    const int l15 = lane & 15, g = lane >> 4;
    const int wm = wid >> 1, wn = wid & 1;
    const int arow = mt * 128 + wm * 32 + l15;
    const float* xr0 = x + (size_t)arow * CC + g * 8;
    const float* xr1 = xr0 + (size_t)16 * CC;

    const f32x4 fz = {0.f, 0.f, 0.f, 0.f};
    f32x4 acc[2][12];
#pragma unroll
    for (int mr = 0; mr < 2; mr++)
#pragma unroll
        for (int nr = 0; nr < 12; nr++) acc[mr][nr] = fz;

    const int swr = wid * 48;
    const short* wsrc = wT + (size_t)(swr + (lane >> 3)) * CC + (lane & 7) * 8;

    float4 pa[2][2][2];
#define LOADA(kc) do { \
    _Pragma("unroll") for (int mr_ = 0; mr_ < 2; mr_++) \
    _Pragma("unroll") for (int ks_ = 0; ks_ < 2; ks_++) { \
        const float* p_ = (mr_ ? xr1 : xr0) + (kc) * 64 + ks_ * 32; \
        pa[mr_][ks_][0] = *(const float4*)p_; \
        pa[mr_][ks_][1] = *(const float4*)(p_ + 4); } \
} while (0)
#define STAGEW(kc, buf) do { \
    _Pragma("unroll") for (int j_ = 0; j_ < 6; j_++) \
        gload_lds16(wsrc + (size_t)(j_ * 8) * CC + (kc) * 64, &lw[buf][(swr + j_ * 8) * 64]); \
} while (0)

    LOADA(0);
    STAGEW(0, 0);
    asm volatile("s_waitcnt vmcnt(0)" ::: "memory");
    __builtin_amdgcn_s_barrier();
    int cur = 0;

    for (int kc = 0; kc < 16; kc++) {
        s16x8 af[2][2];
#pragma unroll
        for (int mr = 0; mr < 2; mr++)
#pragma unroll
            for (int ks = 0; ks < 2; ks++) {
                union { unsigned u[4]; s16x8 v; } cv;
                cv.u[0] = cvt_pk(pa[mr][ks][0].x, pa[mr][ks][0].y);
                cv.u[1] = cvt_pk(pa[mr][ks][0].z, pa[mr][ks][0].w);
                cv.u[2] = cvt_pk(pa[mr][ks][1].x, pa[mr][ks][1].y);
                cv.u[3] = cvt_pk(pa[mr][ks][1].z, pa[mr][ks][1].w);
                af[mr][ks] = cv.v;
            }
        if (kc < 15) { LOADA(kc + 1); STAGEW(kc + 1, cur ^ 1); }
        __builtin_amdgcn_s_setprio(1);
#pragma unroll
        for (int ks = 0; ks < 2; ks++)
#pragma unroll
            for (int nr = 0; nr < 12; nr++) {
                const s16x8 bfg = *(const s16x8*)
                    &lw[cur][(wn * 192 + nr * 16 + l15) * 64 + ks * 32 + g * 8];
                acc[0][nr] = mfma16(af[0][ks], bfg, acc[0][nr]);
                acc[1][nr] = mfma16(af[1][ks], bfg, acc[1][nr]);
            }
        __builtin_amdgcn_s_setprio(0);
        asm volatile("s_waitcnt vmcnt(0) lgkmcnt(0)" ::: "memory");
        __builtin_amdgcn_s_barrier();
        cur ^= 1;
    }

    const int bidx = mt >> 5;
    const int tb = (mt & 31) * 128 + wm * 32;
#pragma unroll
    for (int mr = 0; mr < 2; mr++)
#pragma unroll
        for (int nr = 0; nr < 12; nr++) {
            const int n = wn * 192 + nr * 16 + l15;
            if (n < 256) {
                short* dst; int d;
                if (n < 128) { dst = qo; d = n; } else { dst = ko; d = n - 128; }
#pragma unroll
                for (int i = 0; i < 4; i++) {
                    int t = tb + mr * 16 + g * 4 + i;
                    dst[((size_t)bidx * TT + t) * DD + d] = f2bf(acc[mr][nr][i]);
                }
            } else {
                const int d = n - 256;
                const int t = tb + mr * 16 + g * 4;
                uint2 u;
                u.x = cvt_pk(acc[mr][nr][0], acc[mr][nr][1]);
                u.y = cvt_pk(acc[mr][nr][2], acc[mr][nr][3]);
                *(uint2*)(vTo + ((size_t)bidx * DD + d) * TT + t) = u;   // V^T
            }
        }
}

// ---------------- kernel 2: split-K flash attention, 32 q-rows/wave --------------
// Block = 128-row q-tile (Q=0..31) x kv-chunk c (<=16 tiles) x batch b.
// 4 waves x 32 q-rows (two 16-q groups share every K/V ds_read -> LDS bytes
// per FLOP halved). Single-buffered K and V, 2-barrier schedule with counted
// vmcnt(4): SK(t+1) issued after post-QK barrier (hidden under softmax+PV),
// SV(t+1) after post-PV barrier (hidden under next QK). LDS 48KB -> up to
// 3 blocks/CU. b = id&7 XCD-pins each batch's K/V into one 4MB L2.
__global__ __launch_bounds__(256)
void attn_kernel(const short* __restrict__ qb, const short* __restrict__ kb,
                 const short* __restrict__ vb, float* __restrict__ out,
                 float* __restrict__ opart, float* __restrict__ mlpart) {
    const int id = blockIdx.x;
    const int b  = id & 7;              // batch -> XCD pin
    const int Q  = (id >> 3) & 31;      // 128-row q-tile
    const int c  = id >> 8;             // 0..3
    const int t0 = c * 16;
    const int tend = 2 * Q + 2;
    if (t0 >= tend) return;             // dead chunk: exit before any barrier
    const int t1 = (t0 + 16 < tend) ? t0 + 16 : tend;
    const int nc = (tend + 15) >> 4;    // 1..4

    __shared__ short lk[64 * 128];      // 16KB K tile (single buffer)
    __shared__ short lv[128 * 64];      // 16KB V^T tile (single buffer)
    __shared__ short lp[4][2048];       // 16KB P per wave (2 groups x [16q][64k])
    const int tid = threadIdx.x, lane = tid & 63, wid = tid >> 6;
    const int l15 = lane & 15, g = lane >> 4;
    const int wq0 = Q * 128 + wid * 32;            // wave's 32 q-rows
    const int tqw = wq0 >> 6;                      // wave's diagonal kv-tile
    const short* kT = kb + (size_t)b * TT * DD;
    const short* vT = vb + (size_t)b * DD * TT;
    char* lpw = (char*)&lp[wid][0];
    const f32x4 fz = {0.f, 0.f, 0.f, 0.f};

    // Q fragments for both 16-q groups (pre-scaled by D^-0.5*log2e)
    s16x8 qf0[4], qf1[4];
    {
        const short* qp0 = qb + ((size_t)b * TT + wq0 + l15) * DD + g * 8;
        const short* qp1 = qp0 + 16 * DD;
#pragma unroll
        for (int ks = 0; ks < 4; ks++) {
            qf0[ks] = *(const s16x8*)(qp0 + ks * 32);
            qf1[ks] = *(const s16x8*)(qp1 + ks * 32);
        }
    }
    f32x4 o0[8], o1[8];
#pragma unroll
    for (int n = 0; n < 8; n++) { o0[n] = fz; o1[n] = fz; }
    float rmax0 = -1e30f, rsum0 = 0.f, rmax1 = -1e30f, rsum1 = 0.f;

    // staging: per wave K rows [wid*16,+16) (4 gloads), V rows [wid*32,+32) (4)
#define SK(kv0) do { \
    _Pragma("unroll") for (int j_ = 0; j_ < 4; j_++) { \
        int rbk = wid * 16 + j_ * 4; \
        int rk = rbk + (lane >> 4); \
        int ck = (lane & 15) ^ (rk & 7); \
        gload_lds16(kT + (size_t)((kv0) + rk) * DD + ck * 8, lk + rbk * 128); } \
} while (0)
#define SV(kv0) do { \
    _Pragma("unroll") for (int j_ = 0; j_ < 4; j_++) { \
        int rbv = wid * 32 + j_ * 8; \
        int dv = rbv + (lane >> 3); \
        int cv = (lane & 7) ^ (dv & 7); \
        gload_lds16(vT + (size_t)dv * TT + (kv0) + cv * 8, lv + rbv * 64); } \
} while (0)

    SK(t0 * 64);
    SV(t0 * 64);
    asm volatile("s_waitcnt vmcnt(0)" ::: "memory");
    __builtin_amdgcn_s_barrier();

    for (int t = t0; t < t1; t++) {
        const int kv0 = t * 64;
        const int tn = (t + 1 < 63) ? t + 1 : 63;   // clamped prefetch index
        // drain SK(t) (4 newest = SV(t) may stay in flight)
        asm volatile("s_waitcnt vmcnt(4)" ::: "memory");
        f32x4 s0[4], s1[4];
        if (t <= tqw) {                 // wave-uniform activity test
            __builtin_amdgcn_s_setprio(1);
#pragma unroll
            for (int sub = 0; sub < 4; sub++) {
                f32x4 a0 = fz, a1 = fz;
#pragma unroll
                for (int ks = 0; ks < 4; ks++) {
                    int row = sub * 16 + l15;
                    int byte = (row * 256 + ks * 64 + g * 16) ^ ((row & 7) << 4);
                    s16x8 kf = *(const s16x8*)((const char*)lk + byte);
                    a0 = mfma16(kf, qf0[ks], a0);
                    a1 = mfma16(kf, qf1[ks], a1);
                }
                s0[sub] = a0; s1[sub] = a1;
            }
            __builtin_amdgcn_s_setprio(0);
        }
        __builtin_amdgcn_s_barrier();   // barrier1: all QK reads of lk done
        SK(tn * 64);                    // overwrite lk; hidden under softmax+PV
        if (t <= tqw) {
            if (t == tqw) {             // causal mask (diagonal supertile)
#pragma unroll
                for (int sub = 0; sub < 4; sub++)
#pragma unroll
                    for (int i = 0; i < 4; i++) {
                        int k = kv0 + sub * 16 + 4 * g + i;
                        if (k > wq0 + l15) s0[sub][i] = -1e30f;
                        if (k > wq0 + 16 + l15) s1[sub][i] = -1e30f;
                    }
            }
            // online softmax (base-2), both groups, lane-local q-rows
            float m0 = s0[0][0], m1 = s1[0][0];
#pragma unroll
            for (int sub = 0; sub < 4; sub++)
#pragma unroll
                for (int i = 0; i < 4; i++) {
                    m0 = fmaxf(m0, s0[sub][i]);
                    m1 = fmaxf(m1, s1[sub][i]);
                }
            m0 = fmaxf(m0, __shfl_xor(m0, 16));
            m0 = fmaxf(m0, __shfl_xor(m0, 32));
            m1 = fmaxf(m1, __shfl_xor(m1, 16));
            m1 = fmaxf(m1, __shfl_xor(m1, 32));
            float mn0 = fmaxf(rmax0, m0), mn1 = fmaxf(rmax1, m1);
            float sc0 = exp2f(rmax0 - mn0), sc1 = exp2f(rmax1 - mn1);
            rmax0 = mn0; rmax1 = mn1;
            float ls0 = 0.f, ls1 = 0.f;
#pragma unroll
            for (int sub = 0; sub < 4; sub++)
#pragma unroll
                for (int i = 0; i < 4; i++) {
                    float p0 = exp2f(s0[sub][i] - mn0);
                    float p1 = exp2f(s1[sub][i] - mn1);
                    s0[sub][i] = p0; s1[sub][i] = p1;
                    ls0 += p0; ls1 += p1;
                }
            ls0 += __shfl_xor(ls0, 16); ls0 += __shfl_xor(ls0, 32);
            ls1 += __shfl_xor(ls1, 16); ls1 += __shfl_xor(ls1, 32);
            rsum0 = rsum0 * sc0 + ls0;
            rsum1 = rsum1 * sc1 + ls1;
            // P -> bf16 -> LDS (group h at lpw + h*2048)
#pragma unroll
            for (int sub = 0; sub < 4; sub++) {
                uint2 w0, w1;
                w0.x = cvt_pk(s0[sub][0], s0[sub][1]);
                w0.y = cvt_pk(s0[sub][2], s0[sub][3]);
                w1.x = cvt_pk(s1[sub][0], s1[sub][1]);
                w1.y = cvt_pk(s1[sub][2], s1[sub][3]);
                int byte = (l15 * 128 + sub * 32 + g * 8) ^ ((l15 & 7) << 4);
                *(uint2*)(lpw + byte) = w0;
                *(uint2*)(lpw + 2048 + byte) = w1;
            }
#pragma unroll
            for (int n = 0; n < 8; n++)
#pragma unroll
                for (int i = 0; i < 4; i++) { o0[n][i] *= sc0; o1[n][i] *= sc1; }
        }
        // drain SV(t) (4 newest = SK(tn) stay in flight)
        asm volatile("s_waitcnt vmcnt(4)" ::: "memory");
        if (t <= tqw) {
            // PV swapped: O^T += V^T (A, rows=d) x P^T (B); vf shared by groups
            __builtin_amdgcn_s_setprio(1);
#pragma unroll
            for (int ks2 = 0; ks2 < 2; ks2++) {
                int pbyte = (l15 * 128 + ks2 * 64 + g * 16) ^ ((l15 & 7) << 4);
                s16x8 pf0 = *(const s16x8*)(lpw + pbyte);
                s16x8 pf1 = *(const s16x8*)(lpw + 2048 + pbyte);
#pragma unroll
                for (int n = 0; n < 8; n++) {
                    int vrow = n * 16 + l15;
                    int vbyte = (vrow * 128 + ks2 * 64 + g * 16) ^ ((vrow & 7) << 4);
                    s16x8 vf = *(const s16x8*)((const char*)lv + vbyte);
                    o0[n] = mfma16(vf, pf0, o0[n]);
                    o1[n] = mfma16(vf, pf1, o1[n]);
                }
            }
            __builtin_amdgcn_s_setprio(0);
        }
        __builtin_amdgcn_s_barrier();   // barrier2: all PV reads of lv done
        SV(tn * 64);                    // overwrite lv; hidden under next QK
    }

    // epilogue: group h rows r = wid*32 + h*16 + l15
#pragma unroll
    for (int h = 0; h < 2; h++) {
        const int r = wid * 32 + h * 16 + l15;
        const float rs = h ? rsum1 : rsum0;
        const float rm = h ? rmax1 : rmax0;
        const f32x4* oo = h ? o1 : o0;
        if (nc == 1) {                  // Q <= 7: final output
            float inv = 1.0f / rs;
            float* orow = out + ((size_t)b * TT + Q * 128 + r) * DD;
#pragma unroll
            for (int n = 0; n < 8; n++) {
                f32x4 w;
                w[0] = oo[n][0] * inv; w[1] = oo[n][1] * inv;
                w[2] = oo[n][2] * inv; w[3] = oo[n][3] * inv;
                __builtin_nontemporal_store(w, (f32x4*)(orow + n * 16 + 4 * g));
            }
        } else {                        // partial: raw O + (m,l), non-temporal
            const size_t pb = ((size_t)b * 24 + (Q - 8)) * 4 + c;
            float* prow = opart + pb * (128 * 128) + (size_t)r * 128;
#pragma unroll
            for (int n = 0; n < 8; n++)
                __builtin_nontemporal_store(oo[n], (f32x4*)(prow + n * 16 + 4 * g));
            if (g == 0) {
                f32x2 s2; s2[0] = rm; s2[1] = rs;
                __builtin_nontemporal_store(s2, (f32x2*)(mlpart + (pb * 128 + r) * 2));
            }
        }
    }
}

// ---------------- kernel 3: combine partials (Q >= 8) ----------------------------
__global__ __launch_bounds__(256)
void comb_kernel(const float* __restrict__ opart, const float* __restrict__ mlpart,
                 float* __restrict__ out) {
    const int qh = blockIdx.x;          // 0..47: Q = 8 + (qh>>1), half = qh&1
    const int b = blockIdx.y;
    const int Q = 8 + (qh >> 1);
    const int nc = (2 * Q + 2 + 15) >> 4;   // 2..4
    const int tid = threadIdx.x;
    const int r = (qh & 1) * 64 + (tid >> 2), quad = tid & 3;
    const size_t base = ((size_t)b * 24 + (Q - 8)) * 4;

    float M = -3e38f;
    for (int cc = 0; cc < nc; cc++)
        M = fmaxf(M, mlpart[((base + cc) * 128 + r) * 2]);

    float acc[32];
#pragma unroll
    for (int k = 0; k < 32; k++) acc[k] = 0.f;
    float L = 0.f;
    for (int cc = 0; cc < nc; cc++) {
        float sm = mlpart[((base + cc) * 128 + r) * 2];
        float sl = mlpart[((base + cc) * 128 + r) * 2 + 1];
        float wgt = exp2f(sm - M);
        L += wgt * sl;
        const float* src = opart + (base + cc) * (128 * 128) + (size_t)r * 128 + quad * 32;
#pragma unroll
        for (int k = 0; k < 8; k++) {
            f32x4 v = __builtin_nontemporal_load((const f32x4*)(src + k * 4));
            acc[k * 4 + 0] += wgt * v[0];
            acc[k * 4 + 1] += wgt * v[1];
            acc[k * 4 + 2] += wgt * v[2];
            acc[k * 4 + 3] += wgt * v[3];
        }
    }
    float inv = 1.0f / L;
    float* dst = out + ((size_t)b * TT + Q * 128 + r) * DD + quad * 32;
#pragma unroll
    for (int k = 0; k < 8; k++) {
        f32x4 w;
        w[0] = acc[k * 4 + 0] * inv; w[1] = acc[k * 4 + 1] * inv;
        w[2] = acc[k * 4 + 2] * inv; w[3] = acc[k * 4 + 3] * inv;
        __builtin_nontemporal_store(w, (f32x4*)(dst + k * 4));
    }
}

// ---------------- launch ---------------------------------------------------------
extern "C" void kernel_launch(void* const* d_in, const int* in_sizes, int n_in,
                              void* d_out, int out_size, void* d_ws, size_t ws_size,
                              hipStream_t stream) {
    const float* x  = (const float*)d_in[0];
    const float* wq = (const float*)d_in[1];
    const float* wk = (const float*)d_in[2];
    const float* wv = (const float*)d_in[3];
    float* out = (float*)d_out;
    char* ws = (char*)d_ws;
    // ws: wT 768KB | q 8MB | k 8MB | vT 8MB | Opart 48MB | ML 768KB  (~74MB)
    short* wT = (short*)ws;
    short* qb = (short*)(ws + 786432);
    short* kb = (short*)(ws + 786432 + 8388608);
    short* vb = (short*)(ws + 786432 + 16777216);
    float* opart = (float*)(ws + 786432 + 25165824);
    float* mlpart = (float*)(ws + 786432 + 25165824 + 50331648);

    wt_kernel<<<1536, 256, 0, stream>>>(wq, wk, wv, wT);
    qkv_kernel<<<256, 512, 0, stream>>>(x, wT, qb, kb, vb);
    attn_kernel<<<1024, 256, 0, stream>>>(qb, kb, vb, out, opart, mlpart);
    comb_kernel<<<dim3(48, 8), 256, 0, stream>>>(opart, mlpart, out);
}